// Round 2
// baseline (1132.743 us; speedup 1.0000x reference)
//
#include <hip/hip_runtime.h>
#include <hip/hip_fp16.h>

typedef _Float16 f16;
typedef _Float16 f16x8 __attribute__((ext_vector_type(8)));
typedef float f32x4 __attribute__((ext_vector_type(4)));
typedef float f32x2 __attribute__((ext_vector_type(2)));

#define HDIM 128
#define LAYERS 4
#define TM 64
#define NEG_BIG (-3.0e38f)

static __device__ __forceinline__ f32x4 mfma16(f16x8 a, f16x8 b, f32x4 c) {
  return __builtin_amdgcn_mfma_f32_16x16x32_f16(a, b, c, 0, 0, 0);
}

// sign-aware float atomic max: works because init is NEG_BIG and values are finite.
static __device__ __forceinline__ void atomicMaxF(float* addr, float val) {
  if (val >= 0.f) atomicMax((int*)addr, __float_as_int(val));
  else            atomicMin((unsigned int*)addr, __float_as_uint(val));
}

// ---------------- CSR build (self-loops inlined at slot 0 of each node) ----------------
__global__ void gnn_hist(const int* __restrict__ ei, int* __restrict__ deg, int E) {
  int e = blockIdx.x * 256 + threadIdx.x;
  if (e < E) atomicAdd(&deg[ei[E + e]], 1);
}

// per-256-node block sums of (deg+1)
__global__ void gnn_bsum(const int* __restrict__ deg, int* __restrict__ bsum, int N) {
  __shared__ int red[256];
  int v = blockIdx.x * 256 + threadIdx.x;
  red[threadIdx.x] = (v < N) ? (deg[v] + 1) : 0;
  __syncthreads();
  for (int d = 128; d; d >>= 1) {
    if (threadIdx.x < d) red[threadIdx.x] += red[threadIdx.x + d];
    __syncthreads();
  }
  if (threadIdx.x == 0) bsum[blockIdx.x] = red[0];
}

// single-block scan of <=256 block sums
__global__ void gnn_bscan(const int* __restrict__ bsum, int* __restrict__ boffs,
                          int* __restrict__ offs, int nb, int N) {
  __shared__ int sh[256];
  int t = threadIdx.x;
  sh[t] = (t < nb) ? bsum[t] : 0;
  __syncthreads();
  for (int d = 1; d < 256; d <<= 1) {
    int add = (t >= d) ? sh[t - d] : 0;
    __syncthreads();
    sh[t] += add;
    __syncthreads();
  }
  boffs[t] = (t > 0) ? sh[t - 1] : 0;
  if (t == 255) offs[N] = sh[255];
}

// per-block scan -> offs, cursor (past self slot), self colsrc, nodeof fill
__global__ void gnn_scan_fin(const int* __restrict__ deg, const int* __restrict__ boffs,
                             int* __restrict__ offs, int* __restrict__ cursor,
                             int* __restrict__ colsrc, int* __restrict__ nodeof, int N) {
  __shared__ int sh[256];
  int t = threadIdx.x;
  int v = blockIdx.x * 256 + t;
  int val = (v < N) ? (deg[v] + 1) : 0;
  sh[t] = val;
  __syncthreads();
  for (int d = 1; d < 256; d <<= 1) {
    int add = (t >= d) ? sh[t - d] : 0;
    __syncthreads();
    sh[t] += add;
    __syncthreads();
  }
  if (v < N) {
    int excl = boffs[blockIdx.x] + sh[t] - val;
    offs[v] = excl;
    cursor[v] = excl + 1;       // slot 0 = self loop
    colsrc[excl] = v;
    int e = excl + val;
    for (int s = excl; s < e; s++) nodeof[s] = v;
  }
}

__global__ void gnn_scatter(const int* __restrict__ ei, int* __restrict__ cursor,
                            int* __restrict__ colsrc, int E) {
  int e = blockIdx.x * 256 + threadIdx.x;
  if (e < E) {
    int d = ei[E + e];
    int p = atomicAdd(&cursor[d], 1);
    colsrc[p] = ei[e];
  }
}

// ---------------- weight prep: fragment-ordered f16 hi/lo planes ----------------
__global__ void gnn_wprep1(const float* __restrict__ W1, f16* __restrict__ Wc) {
  int id = blockIdx.x * 256 + threadIdx.x;
  if (id >= LAYERS * 128 * 256) return;
  int col = id & 255, k = (id >> 8) & 127, l = id >> 15;
  float w;
  if (col < 128) w = W1[((size_t)l * 256 + k) * 128 + col] - W1[((size_t)l * 256 + 128 + k) * 128 + col];
  else           w = W1[((size_t)l * 256 + 128 + k) * 128 + (col - 128)];
  f16 hi = (f16)w;
  f16 lo = (f16)(w - (float)hi);
  int kk = k >> 5, quad = (k >> 3) & 3, j = k & 7;
  int ntile = col >> 4, lane = quad * 16 + (col & 15);
  size_t base = ((((size_t)l * 2 + 0) * 4 + kk) * 16 + ntile) * 512 + lane * 8 + j;
  Wc[base] = hi;
  Wc[base + (size_t)4 * 16 * 512] = lo;
}

__global__ void gnn_wprep2(const float* __restrict__ W2, f16* __restrict__ W2f) {
  int id = blockIdx.x * 256 + threadIdx.x;
  if (id >= LAYERS * 128 * 128) return;
  int n = id & 127, k = (id >> 7) & 127, l = id >> 14;
  float w = W2[((size_t)l * 128 + k) * 128 + n];
  f16 hi = (f16)w;
  f16 lo = (f16)(w - (float)hi);
  int kk = k >> 5, quad = (k >> 3) & 3, j = k & 7;
  int ntile = n >> 4, lane = quad * 16 + (n & 15);
  size_t base = ((((size_t)l * 2 + 0) * 4 + kk) * 8 + ntile) * 512 + lane * 8 + j;
  W2f[base] = hi;
  W2f[base + (size_t)4 * 8 * 512] = lo;
}

// ---------------- per-layer node GEMM: P = x@(W1a-W1b)+b1, Q = x@W1b ----------------
__global__ __launch_bounds__(256) void gnn_pq(const float* __restrict__ x,
    const f16* __restrict__ Wc, const float* __restrict__ b1,
    float* __restrict__ P, float* __restrict__ Q, int N) {
  __shared__ __align__(16) f16 shA[2 * 4 * 4 * 64 * 8];
  int tid = threadIdx.x;
  int row0 = blockIdx.x * 64;
#pragma unroll
  for (int i = 0; i < 4; i++) {
    int p = i * 256 + tid;
    int row = p & 63, seg = p >> 6;
    float v[8];
    int gr = row0 + row;
    if (gr < N) {
      const f32x4* xp = (const f32x4*)(x + (size_t)gr * HDIM + seg * 8);
      f32x4 a = xp[0], b = xp[1];
      v[0]=a.x; v[1]=a.y; v[2]=a.z; v[3]=a.w; v[4]=b.x; v[5]=b.y; v[6]=b.z; v[7]=b.w;
    } else {
#pragma unroll
      for (int j = 0; j < 8; j++) v[j] = 0.f;
    }
    f16x8 hv, lv;
#pragma unroll
    for (int j = 0; j < 8; j++) { f16 h = (f16)v[j]; hv[j] = h; lv[j] = (f16)(v[j] - (float)h); }
    int kk = seg >> 2, quad = seg & 3, mt = row >> 4, m = row & 15;
    int lane = quad * 16 + m;
    int off = ((kk * 4 + mt) * 64 + lane) * 8;
    *(f16x8*)&shA[off] = hv;
    *(f16x8*)&shA[off + 4 * 4 * 64 * 8] = lv;
  }
  __syncthreads();
  int wave = tid >> 6, lane = tid & 63;
  int quad = lane >> 4, cl = lane & 15;
  f16x8 bw[2][4][4];
#pragma unroll
  for (int pl = 0; pl < 2; pl++)
#pragma unroll
    for (int nt = 0; nt < 4; nt++)
#pragma unroll
      for (int kk = 0; kk < 4; kk++) {
        int ntile = wave * 4 + nt;
        bw[pl][nt][kk] = *(const f16x8*)&Wc[(((size_t)(pl * 4 + kk) * 16 + ntile) * 64 + lane) * 8];
      }
#pragma unroll
  for (int mt = 0; mt < 4; mt++) {
    f32x4 acc[4] = {};
#pragma unroll
    for (int kk = 0; kk < 4; kk++) {
      f16x8 ah = *(const f16x8*)&shA[((kk * 4 + mt) * 64 + lane) * 8];
      f16x8 al = *(const f16x8*)&shA[(((4 + kk) * 4 + mt) * 64 + lane) * 8];
#pragma unroll
      for (int nt = 0; nt < 4; nt++) {
        acc[nt] = mfma16(ah, bw[0][nt][kk], acc[nt]);
        acc[nt] = mfma16(al, bw[0][nt][kk], acc[nt]);
        acc[nt] = mfma16(ah, bw[1][nt][kk], acc[nt]);
      }
    }
#pragma unroll
    for (int nt = 0; nt < 4; nt++) {
      int c = (wave * 4 + nt) * 16 + cl;
      float bb = (c < HDIM) ? b1[c] : 0.f;
      float* dst = (c < HDIM) ? P : Q;
      int cc = c & 127;
#pragma unroll
      for (int i = 0; i < 4; i++) {
        int gr = row0 + mt * 16 + quad * 4 + i;
        if (gr < N) dst[(size_t)gr * HDIM + cc] = acc[nt][i] + bb;
      }
    }
  }
}

// ---------------- straddler init (-inf) / fixup (+b2) ----------------
__global__ void gnn_initstrad(const int* __restrict__ offs, float* __restrict__ xout, int N) {
  int id = blockIdx.x * 256 + threadIdx.x;
  if (id >= N * 32) return;
  int v = id >> 5, c4 = (id & 31) << 2;
  int a = offs[v], b = offs[v + 1] - 1;
  if (a / TM != b / TM) {
    f32x4 ninf = {NEG_BIG, NEG_BIG, NEG_BIG, NEG_BIG};
    *(f32x4*)&xout[(size_t)v * HDIM + c4] = ninf;
  }
}

__global__ void gnn_fixup(const int* __restrict__ offs, const float* __restrict__ b2,
                          float* __restrict__ xout, int N) {
  int id = blockIdx.x * 256 + threadIdx.x;
  if (id >= N * 32) return;
  int v = id >> 5, c4 = (id & 31) << 2;
  int a = offs[v], b = offs[v + 1] - 1;
  if (a / TM != b / TM) {
    float* p = &xout[(size_t)v * HDIM + c4];
    f32x4 x = *(f32x4*)p;
    const f32x4 bb = *(const f32x4*)&b2[c4];
    x.x += bb.x; x.y += bb.y; x.z += bb.z; x.w += bb.w;
    *(f32x4*)p = x;
  }
}

// ---------------- slot-parallel edge MLP + segmented max ----------------
// one block = 64 consecutive CSR slots. coalesced gather -> swizzled A-frag LDS ->
// 64x128x128 3-term GEMM -> C to LDS (swizzled) -> segmented max -> store/atomic.
__global__ __launch_bounds__(256) void gnn_edge2(
    const float* __restrict__ P, const float* __restrict__ Q,
    const int* __restrict__ offs, const int* __restrict__ colsrc,
    const int* __restrict__ nodeof, const f16* __restrict__ W2f,
    const float* __restrict__ b2, float* __restrict__ xout, int S) {
  __shared__ __align__(16) char smem[32768];
  f16* shA = (f16*)smem;       // [plane(2)][kk(4)][mt(4)][flS(64)][8] f16
  float* msg = (float*)smem;   // reused after barrier: [64][128] swizzled
  int tid = threadIdx.x;
  int wave = tid >> 6, lane = tid & 63;
  int quad = lane >> 4, cl = lane & 15;
  // B fragments (W2 hi/lo, fragment-ordered, L2-hot)
  f16x8 bw[2][2][4];
#pragma unroll
  for (int pl = 0; pl < 2; pl++)
#pragma unroll
    for (int nt = 0; nt < 2; nt++)
#pragma unroll
      for (int kk = 0; kk < 4; kk++)
        bw[pl][nt][kk] = *(const f16x8*)&W2f[(((size_t)(pl * 4 + kk) * 8 + (wave * 2 + nt)) * 64 + lane) * 8];
  int t0 = blockIdx.x * TM;
  // ---- build A frags: 16 consecutive lanes cover one slot's 512B row (coalesced) ----
  int seg = tid & 15, kkb = seg >> 2, qb = seg & 3, mrow = tid >> 4;
  int fl = qb * 16 + mrow;
  int flS = fl ^ kkb ^ ((fl >> 4) << 2);   // bank-uniform XOR swizzle
#pragma unroll
  for (int i = 0; i < 4; i++) {
    int s = t0 + i * 16 + mrow;
    f16x8 hv = {}, lv = {};
    if (s < S) {
      int src = colsrc[s];
      int dst = nodeof[s];
      const f32x4* qp = (const f32x4*)(Q + (size_t)src * HDIM + seg * 8);
      const f32x4* pp = (const f32x4*)(P + (size_t)dst * HDIM + seg * 8);
      f32x4 qa = qp[0], qb4 = qp[1], pa = pp[0], pb = pp[1];
      float pre[8] = {pa.x + qa.x, pa.y + qa.y, pa.z + qa.z, pa.w + qa.w,
                      pb.x + qb4.x, pb.y + qb4.y, pb.z + qb4.z, pb.w + qb4.w};
#pragma unroll
      for (int j = 0; j < 8; j++) {
        float v = fmaxf(pre[j], 0.f);
        f16 h = (f16)v; hv[j] = h; lv[j] = (f16)(v - (float)h);
      }
    }
    int off = ((kkb * 4 + i) * 64 + flS) * 8;
    *(f16x8*)&shA[off] = hv;
    *(f16x8*)&shA[off + 8192] = lv;   // lo plane
  }
  __syncthreads();
  // ---- GEMM: wave covers cols [wave*32, wave*32+32) ----
  f32x4 acc[4][2] = {};
  int swz = ((lane >> 4) & 3) << 2;
#pragma unroll
  for (int kk = 0; kk < 4; kk++) {
    int fls = lane ^ kk ^ swz;
#pragma unroll
    for (int mt = 0; mt < 4; mt++) {
      int off = ((kk * 4 + mt) * 64 + fls) * 8;
      f16x8 ah = *(const f16x8*)&shA[off];
      f16x8 al = *(const f16x8*)&shA[off + 8192];
#pragma unroll
      for (int nt = 0; nt < 2; nt++) {
        acc[mt][nt] = mfma16(ah, bw[0][nt][kk], acc[mt][nt]);
        acc[mt][nt] = mfma16(al, bw[0][nt][kk], acc[mt][nt]);
        acc[mt][nt] = mfma16(ah, bw[1][nt][kk], acc[mt][nt]);
      }
    }
  }
  __syncthreads();
  // ---- C -> LDS, row-major [64][128], col XOR-swizzled by row (bank-uniform) ----
#pragma unroll
  for (int mt = 0; mt < 4; mt++)
#pragma unroll
    for (int nt = 0; nt < 2; nt++)
#pragma unroll
      for (int i = 0; i < 4; i++) {
        int row = mt * 16 + quad * 4 + i;
        int col = wave * 32 + nt * 16 + cl;
        msg[row * 128 + (col ^ ((row & 7) << 2))] = acc[mt][nt][i];
      }
  __syncthreads();
  // ---- segmented max over nodes present in this tile ----
  int tEnd = (t0 + TM < S) ? (t0 + TM) : S;
  int vFirst = nodeof[t0];
  int vLast = nodeof[tEnd - 1];
  int npairs = (vLast - vFirst + 1) * HDIM;
  for (int p = tid; p < npairs; p += 256) {
    int v = vFirst + (p >> 7), col = p & 127;
    int a = offs[v], b = offs[v + 1];
    int r0 = (a > t0 ? a : t0) - t0;
    int r1 = (b < tEnd ? b : tEnd) - t0;
    float m = NEG_BIG;
    for (int r = r0; r < r1; r++)
      m = fmaxf(m, msg[r * 128 + (col ^ ((r & 7) << 2))]);
    if (a < t0 || b > t0 + TM) {
      atomicMaxF(&xout[(size_t)v * HDIM + col], m);   // straddler: b2 added by fixup
    } else {
      xout[(size_t)v * HDIM + col] = m + b2[col];
    }
  }
}

// ---------------- final fc: out = x @ Wf + bf ----------------
__global__ __launch_bounds__(256) void gnn_fc(const float* __restrict__ x,
    const float* __restrict__ Wf, const float* __restrict__ bfv,
    float* __restrict__ out, int N) {
  int wave = threadIdx.x >> 6, lane = threadIdx.x & 63;
  int wid = blockIdx.x * 4 + wave, nw = gridDim.x * 4;
  int k0 = lane * 2;
  float w00 = Wf[k0 * 3 + 0], w01 = Wf[k0 * 3 + 1], w02 = Wf[k0 * 3 + 2];
  float w10 = Wf[k0 * 3 + 3], w11 = Wf[k0 * 3 + 4], w12 = Wf[k0 * 3 + 5];
  float bf0 = bfv[0], bf1 = bfv[1], bf2 = bfv[2];
  for (int v = wid; v < N; v += nw) {
    f32x2 xx = *(const f32x2*)(x + (size_t)v * HDIM + k0);
    float d0 = xx.x * w00 + xx.y * w10;
    float d1 = xx.x * w01 + xx.y * w11;
    float d2 = xx.x * w02 + xx.y * w12;
#pragma unroll
    for (int s = 32; s; s >>= 1) {
      d0 += __shfl_xor(d0, s, 64);
      d1 += __shfl_xor(d1, s, 64);
      d2 += __shfl_xor(d2, s, 64);
    }
    if (lane == 0) {
      out[(size_t)v * 3 + 0] = d0 + bf0;
      out[(size_t)v * 3 + 1] = d1 + bf1;
      out[(size_t)v * 3 + 2] = d2 + bf2;
    }
  }
}

extern "C" void kernel_launch(void* const* d_in, const int* in_sizes, int n_in,
                              void* d_out, int out_size, void* d_ws, size_t ws_size,
                              hipStream_t stream) {
  const float* x_in = (const float*)d_in[0];
  const int*   ei   = (const int*)d_in[1];
  const float* W1   = (const float*)d_in[2];
  const float* b1   = (const float*)d_in[3];
  const float* W2   = (const float*)d_in[4];
  const float* b2   = (const float*)d_in[5];
  const float* Wf   = (const float*)d_in[6];
  const float* bfv  = (const float*)d_in[7];
  float* outp = (float*)d_out;
  int N = in_sizes[0] / HDIM;
  int E = in_sizes[1] / 2;
  int S = E + N;

  char* ws = (char*)d_ws;
  size_t o = 0;
  auto alloc = [&](size_t bytes) -> char* {
    char* p = ws + o;
    o += (bytes + 255) & ~(size_t)255;
    return p;
  };
  int*   deg    = (int*)alloc((size_t)N * 4);
  int*   offs   = (int*)alloc(((size_t)N + 1) * 4);
  int*   cursor = (int*)alloc((size_t)N * 4);
  int*   colsrc = (int*)alloc((size_t)S * 4);
  int*   nodeof = (int*)alloc((size_t)S * 4);
  int*   bsum   = (int*)alloc(256 * 4);
  int*   boffs  = (int*)alloc(256 * 4);
  float* P      = (float*)alloc((size_t)N * HDIM * 4);
  float* Q      = (float*)alloc((size_t)N * HDIM * 4);
  float* xbuf   = (float*)alloc((size_t)N * HDIM * 4);
  f16*   Wc     = (f16*)alloc((size_t)LAYERS * 65536 * 2);
  f16*   W2f    = (f16*)alloc((size_t)LAYERS * 32768 * 2);
  (void)ws_size; (void)n_in; (void)out_size;

  int nb = (N + 255) / 256;
  hipMemsetAsync(deg, 0, (size_t)N * 4, stream);
  gnn_hist<<<(E + 255) / 256, 256, 0, stream>>>(ei, deg, E);
  gnn_bsum<<<nb, 256, 0, stream>>>(deg, bsum, N);
  gnn_bscan<<<1, 256, 0, stream>>>(bsum, boffs, offs, nb, N);
  gnn_scan_fin<<<nb, 256, 0, stream>>>(deg, boffs, offs, cursor, colsrc, nodeof, N);
  gnn_scatter<<<(E + 255) / 256, 256, 0, stream>>>(ei, cursor, colsrc, E);
  gnn_wprep1<<<(LAYERS * 128 * 256 + 255) / 256, 256, 0, stream>>>(W1, Wc);
  gnn_wprep2<<<(LAYERS * 128 * 128 + 255) / 256, 256, 0, stream>>>(W2, W2f);

  int nT = (S + TM - 1) / TM;
  int gStrad = (N * 32 + 255) / 256;
  const float* xc = x_in;
  for (int l = 0; l < LAYERS; l++) {
    gnn_pq<<<(N + 63) / 64, 256, 0, stream>>>(xc, Wc + (size_t)l * 65536, b1 + (size_t)l * HDIM, P, Q, N);
    gnn_initstrad<<<gStrad, 256, 0, stream>>>(offs, xbuf, N);
    gnn_edge2<<<nT, 256, 0, stream>>>(P, Q, offs, colsrc, nodeof, W2f + (size_t)l * 32768,
                                      b2 + (size_t)l * HDIM, xbuf, S);
    gnn_fixup<<<gStrad, 256, 0, stream>>>(offs, b2 + (size_t)l * HDIM, xbuf, N);
    xc = xbuf;
  }
  gnn_fc<<<256, 256, 0, stream>>>(xc, Wf, bfv, outp, N);
}

// Round 4
// 867.549 us; speedup vs baseline: 1.3057x; 1.3057x over previous
//
#include <hip/hip_runtime.h>
#include <hip/hip_fp16.h>

typedef _Float16 f16;
typedef _Float16 f16x8 __attribute__((ext_vector_type(8)));
typedef __fp16 hf16x2 __attribute__((ext_vector_type(2)));
typedef float f32x4 __attribute__((ext_vector_type(4)));
typedef float f32x2 __attribute__((ext_vector_type(2)));

#define HDIM 128
#define LAYERS 4
#define NEG_BIG (-3.0e38f)

static __device__ __forceinline__ f32x4 mfma16(f16x8 a, f16x8 b, f32x4 c) {
  return __builtin_amdgcn_mfma_f32_16x16x32_f16(a, b, c, 0, 0, 0);
}

static __device__ __forceinline__ void atomicMaxF(float* addr, float val) {
  if (val >= 0.f) atomicMax((int*)addr, __float_as_int(val));
  else            atomicMin((unsigned int*)addr, __float_as_uint(val));
}

// split two f32x4 into f16 hi/lo planes (packed converts)
static __device__ __forceinline__ void split8(f32x4 a, f32x4 b, f16x8& hv, f16x8& lv) {
  hf16x2 h0 = __builtin_amdgcn_cvt_pkrtz(a.x, a.y);
  hf16x2 h1 = __builtin_amdgcn_cvt_pkrtz(a.z, a.w);
  hf16x2 h2 = __builtin_amdgcn_cvt_pkrtz(b.x, b.y);
  hf16x2 h3 = __builtin_amdgcn_cvt_pkrtz(b.z, b.w);
  hv[0]=(f16)h0[0]; hv[1]=(f16)h0[1]; hv[2]=(f16)h1[0]; hv[3]=(f16)h1[1];
  hv[4]=(f16)h2[0]; hv[5]=(f16)h2[1]; hv[6]=(f16)h3[0]; hv[7]=(f16)h3[1];
  hf16x2 l0 = __builtin_amdgcn_cvt_pkrtz(a.x-(float)h0[0], a.y-(float)h0[1]);
  hf16x2 l1 = __builtin_amdgcn_cvt_pkrtz(a.z-(float)h1[0], a.w-(float)h1[1]);
  hf16x2 l2 = __builtin_amdgcn_cvt_pkrtz(b.x-(float)h2[0], b.y-(float)h2[1]);
  hf16x2 l3 = __builtin_amdgcn_cvt_pkrtz(b.z-(float)h3[0], b.w-(float)h3[1]);
  lv[0]=(f16)l0[0]; lv[1]=(f16)l0[1]; lv[2]=(f16)l1[0]; lv[3]=(f16)l1[1];
  lv[4]=(f16)l2[0]; lv[5]=(f16)l2[1]; lv[6]=(f16)l3[0]; lv[7]=(f16)l3[1];
}

// ---------------- CSR build (self-loops at slot 0 of each node) ----------------
__global__ void gnn_hist(const int* __restrict__ ei, int* __restrict__ deg, int E) {
  int e = blockIdx.x * 256 + threadIdx.x;
  if (e < E) atomicAdd(&deg[ei[E + e]], 1);
}

__global__ void gnn_bsum(const int* __restrict__ deg, int* __restrict__ bsum, int N) {
  __shared__ int red[256];
  int v = blockIdx.x * 256 + threadIdx.x;
  red[threadIdx.x] = (v < N) ? (deg[v] + 1) : 0;
  __syncthreads();
  for (int d = 128; d; d >>= 1) {
    if (threadIdx.x < d) red[threadIdx.x] += red[threadIdx.x + d];
    __syncthreads();
  }
  if (threadIdx.x == 0) bsum[blockIdx.x] = red[0];
}

__global__ void gnn_bscan(const int* __restrict__ bsum, int* __restrict__ boffs,
                          int* __restrict__ offs, int nb, int N) {
  __shared__ int sh[256];
  int t = threadIdx.x;
  sh[t] = (t < nb) ? bsum[t] : 0;
  __syncthreads();
  for (int d = 1; d < 256; d <<= 1) {
    int add = (t >= d) ? sh[t - d] : 0;
    __syncthreads();
    sh[t] += add;
    __syncthreads();
  }
  boffs[t] = (t > 0) ? sh[t - 1] : 0;
  if (t == 255) offs[N] = sh[255];
}

__global__ void gnn_scan_fin(const int* __restrict__ deg, const int* __restrict__ boffs,
                             int* __restrict__ offs, int* __restrict__ cursor,
                             int* __restrict__ colsrc, int* __restrict__ nodeof, int N) {
  __shared__ int sh[256];
  int t = threadIdx.x;
  int v = blockIdx.x * 256 + t;
  int val = (v < N) ? (deg[v] + 1) : 0;
  sh[t] = val;
  __syncthreads();
  for (int d = 1; d < 256; d <<= 1) {
    int add = (t >= d) ? sh[t - d] : 0;
    __syncthreads();
    sh[t] += add;
    __syncthreads();
  }
  if (v < N) {
    int excl = boffs[blockIdx.x] + sh[t] - val;
    offs[v] = excl;
    cursor[v] = excl + 1;       // slot 0 = self loop
    colsrc[excl] = v;
    int e = excl + val;
    for (int s = excl; s < e; s++) nodeof[s] = v;
  }
}

__global__ void gnn_scatter(const int* __restrict__ ei, int* __restrict__ cursor,
                            int* __restrict__ colsrc, int E) {
  int e = blockIdx.x * 256 + threadIdx.x;
  if (e < E) {
    int d = ei[E + e];
    int p = atomicAdd(&cursor[d], 1);
    colsrc[p] = ei[e];
  }
}

// ---------------- bias push-down precompute ----------------
// cbias[l][c]: c<128 -> b1[l]+b2[l-1]@W1d[l];  c>=128 -> b2[l-1]@W1b[l]
// bfp = bf + b2[3]@Wf
__global__ void gnn_biasprep(const float* __restrict__ W1, const float* __restrict__ b1,
                             const float* __restrict__ b2, const float* __restrict__ Wf,
                             const float* __restrict__ bf, float* __restrict__ cbias,
                             float* __restrict__ bfp) {
  int l = blockIdx.x, c = threadIdx.x;
  if (l < LAYERS) {
    float s = 0.f;
    if (l > 0) {
      const float* bp = b2 + (size_t)(l - 1) * HDIM;
      if (c < 128) {
        for (int k = 0; k < 128; k++)
          s += bp[k] * (W1[((size_t)l * 256 + k) * 128 + c] - W1[((size_t)l * 256 + 128 + k) * 128 + c]);
      } else {
        int cc = c - 128;
        for (int k = 0; k < 128; k++)
          s += bp[k] * W1[((size_t)l * 256 + 128 + k) * 128 + cc];
      }
    }
    float base = (c < 128) ? b1[(size_t)l * HDIM + c] : 0.f;
    cbias[l * 256 + c] = base + s;
  } else if (c < 3) {
    float s = bf[c];
    for (int k = 0; k < 128; k++) s += b2[3 * HDIM + k] * Wf[k * 3 + c];
    bfp[c] = s;
  }
}

// ---------------- weight prep: fragment-ordered f16 hi/lo planes ----------------
__global__ void gnn_wprep1(const float* __restrict__ W1, f16* __restrict__ Wc) {
  int id = blockIdx.x * 256 + threadIdx.x;
  if (id >= LAYERS * 128 * 256) return;
  int col = id & 255, k = (id >> 8) & 127, l = id >> 15;
  float w;
  if (col < 128) w = W1[((size_t)l * 256 + k) * 128 + col] - W1[((size_t)l * 256 + 128 + k) * 128 + col];
  else           w = W1[((size_t)l * 256 + 128 + k) * 128 + (col - 128)];
  f16 hi = (f16)w;
  f16 lo = (f16)(w - (float)hi);
  int kk = k >> 5, quad = (k >> 3) & 3, j = k & 7;
  int ntile = col >> 4, lane = quad * 16 + (col & 15);
  size_t base = ((((size_t)l * 2 + 0) * 4 + kk) * 16 + ntile) * 512 + lane * 8 + j;
  Wc[base] = hi;
  Wc[base + (size_t)4 * 16 * 512] = lo;
}

__global__ void gnn_wprep2(const float* __restrict__ W2, f16* __restrict__ W2f) {
  int id = blockIdx.x * 256 + threadIdx.x;
  if (id >= LAYERS * 128 * 128) return;
  int n = id & 127, k = (id >> 7) & 127, l = id >> 14;
  float w = W2[((size_t)l * 128 + k) * 128 + n];
  f16 hi = (f16)w;
  f16 lo = (f16)(w - (float)hi);
  int kk = k >> 5, quad = (k >> 3) & 3, j = k & 7;
  int ntile = n >> 4, lane = quad * 16 + (n & 15);
  size_t base = ((((size_t)l * 2 + 0) * 4 + kk) * 8 + ntile) * 512 + lane * 8 + j;
  W2f[base] = hi;
  W2f[base + (size_t)4 * 8 * 512] = lo;
}

// ---------------- per-layer node GEMM: P = x@W1d + c1, Q = x@W1b + c2 ----------------
// also: init xnext rows of block-straddling nodes to NEG_BIG (for edge atomics)
__global__ __launch_bounds__(256) void gnn_pq(const float* __restrict__ x,
    const f16* __restrict__ Wc, const float* __restrict__ cbias,
    float* __restrict__ P, float* __restrict__ Q, int N,
    const int* __restrict__ offs, int spb, float* __restrict__ xinit) {
  __shared__ __align__(16) f16 shA[2 * 4 * 4 * 64 * 8];
  int tid = threadIdx.x;
  int row0 = blockIdx.x * 64;
#pragma unroll
  for (int i = 0; i < 4; i++) {
    int p = i * 256 + tid;
    int row = p & 63, seg = p >> 6;
    f32x4 a = {}, b = {};
    int gr = row0 + row;
    if (gr < N) {
      const f32x4* xp = (const f32x4*)(x + (size_t)gr * HDIM + seg * 8);
      a = xp[0]; b = xp[1];
    }
    f16x8 hv, lv;
    split8(a, b, hv, lv);
    int kk = seg >> 2, quad = seg & 3, mt = row >> 4, m = row & 15;
    int lane = quad * 16 + m;
    int off = ((kk * 4 + mt) * 64 + lane) * 8;
    *(f16x8*)&shA[off] = hv;
    *(f16x8*)&shA[off + 4 * 4 * 64 * 8] = lv;
  }
  __syncthreads();
  int wave = tid >> 6, lane = tid & 63;
  int quad = lane >> 4, cl = lane & 15;
  f16x8 bw[2][4][4];
#pragma unroll
  for (int pl = 0; pl < 2; pl++)
#pragma unroll
    for (int nt = 0; nt < 4; nt++)
#pragma unroll
      for (int kk = 0; kk < 4; kk++) {
        int ntile = wave * 4 + nt;
        bw[pl][nt][kk] = *(const f16x8*)&Wc[(((size_t)(pl * 4 + kk) * 16 + ntile) * 64 + lane) * 8];
      }
#pragma unroll
  for (int mt = 0; mt < 4; mt++) {
    f32x4 acc[4] = {};
#pragma unroll
    for (int kk = 0; kk < 4; kk++) {
      f16x8 ah = *(const f16x8*)&shA[((kk * 4 + mt) * 64 + lane) * 8];
      f16x8 al = *(const f16x8*)&shA[(((4 + kk) * 4 + mt) * 64 + lane) * 8];
#pragma unroll
      for (int nt = 0; nt < 4; nt++) {
        acc[nt] = mfma16(ah, bw[0][nt][kk], acc[nt]);
        acc[nt] = mfma16(al, bw[0][nt][kk], acc[nt]);
        acc[nt] = mfma16(ah, bw[1][nt][kk], acc[nt]);
      }
    }
#pragma unroll
    for (int nt = 0; nt < 4; nt++) {
      int c = (wave * 4 + nt) * 16 + cl;
      float bb = cbias[c];
      float* dst = (c < HDIM) ? P : Q;
      int cc = c & 127;
#pragma unroll
      for (int i = 0; i < 4; i++) {
        int gr = row0 + mt * 16 + quad * 4 + i;
        if (gr < N) dst[(size_t)gr * HDIM + cc] = acc[nt][i] + bb;
      }
    }
  }
  // init straddler rows of xinit to NEG_BIG (rare: ~2% of nodes)
  if (tid < 64) {
    int v = row0 + tid;
    if (v < N) {
      int a = offs[v], b = offs[v + 1] - 1;
      if (a / spb != b / spb) {
        f32x4 ninf = {NEG_BIG, NEG_BIG, NEG_BIG, NEG_BIG};
        float* xr = xinit + (size_t)v * HDIM;
#pragma unroll
        for (int c = 0; c < HDIM; c += 4) *(f32x4*)(xr + c) = ninf;
      }
    }
  }
}

// ---------------- persistent slot-tile edge MLP + segmented max ----------------
// block owns slots [blk0, blk1), loops 32-slot tiles. build -> B1 -> GEMM ->
// C->msg -> B2 -> segmented max with LDS carry chain; block-boundary nodes via atomicMaxF.
__global__ __launch_bounds__(256, 3) void gnn_edge3(
    const float* __restrict__ P, const float* __restrict__ Q,
    const int* __restrict__ offs, const int* __restrict__ colsrc,
    const int* __restrict__ nodeof, const f16* __restrict__ W2f,
    float* __restrict__ xout, int S, int spb) {
  __shared__ __align__(16) f16 shA[2 * 4 * 2 * 64 * 8];   // [plane][kk][mt][fl][8] = 16KB
  __shared__ float msg[32 * 132];                          // padded stride 132
  __shared__ float stradV[2][128];
  __shared__ int stradN[2];
  int tid = threadIdx.x;
  int wave = tid >> 6, lane = tid & 63;
  int quad = lane >> 4, cl = lane & 15;
  f16x8 bw[2][2][4];
#pragma unroll
  for (int pl = 0; pl < 2; pl++)
#pragma unroll
    for (int nt = 0; nt < 2; nt++)
#pragma unroll
      for (int kk = 0; kk < 4; kk++)
        bw[pl][nt][kk] = *(const f16x8*)&W2f[(((size_t)(pl * 4 + kk) * 8 + (wave * 2 + nt)) * 64 + lane) * 8];
  int blk0 = blockIdx.x * spb;
  int blk1 = blk0 + spb; if (blk1 > S) blk1 = S;
  if (tid < 2) stradN[tid] = -1;
  int sl = tid >> 4, seg = tid & 15;
  int kkb = seg >> 2, qb = seg & 3;
  int laneF = qb * 16 + sl;
  int tc = 0;
  for (int t0 = blk0; t0 < blk1; t0 += 32, tc++) {
    int par = tc & 1, prv = par ^ 1;
    int tEnd = t0 + 32; if (tEnd > blk1) tEnd = blk1;
    // ---- build: 16 consecutive lanes cover one slot's 512B row ----
#pragma unroll
    for (int i = 0; i < 2; i++) {
      int slot = t0 + i * 16 + sl;
      int slc = (slot < S) ? slot : (S - 1);
      int src = colsrc[slc];
      int dst = nodeof[slc];
      const f32x4* qp = (const f32x4*)(Q + (size_t)src * HDIM + seg * 8);
      const f32x4* pp = (const f32x4*)(P + (size_t)dst * HDIM + seg * 8);
      f32x4 qa = qp[0], qb4 = qp[1], pa = pp[0], pb = pp[1];
      f32x4 sa, sb;
      sa.x = fmaxf(pa.x + qa.x, 0.f); sa.y = fmaxf(pa.y + qa.y, 0.f);
      sa.z = fmaxf(pa.z + qa.z, 0.f); sa.w = fmaxf(pa.w + qa.w, 0.f);
      sb.x = fmaxf(pb.x + qb4.x, 0.f); sb.y = fmaxf(pb.y + qb4.y, 0.f);
      sb.z = fmaxf(pb.z + qb4.z, 0.f); sb.w = fmaxf(pb.w + qb4.w, 0.f);
      f16x8 hv, lv;
      split8(sa, sb, hv, lv);
      int off = ((kkb * 2 + i) * 64 + laneF) * 8;
      *(f16x8*)&shA[off] = hv;
      *(f16x8*)&shA[off + 4096] = lv;
    }
    __syncthreads();                     // B1
    if (tid == 0) stradN[par] = -1;
    // ---- GEMM: wave covers cols [wave*32, wave*32+32) ----
    f32x4 acc[2][2] = {};
#pragma unroll
    for (int kk = 0; kk < 4; kk++)
#pragma unroll
      for (int mt = 0; mt < 2; mt++) {
        int off = ((kk * 2 + mt) * 64 + lane) * 8;
        f16x8 ah = *(const f16x8*)&shA[off];
        f16x8 al = *(const f16x8*)&shA[off + 4096];
#pragma unroll
        for (int nt = 0; nt < 2; nt++) {
          acc[mt][nt] = mfma16(ah, bw[0][nt][kk], acc[mt][nt]);
          acc[mt][nt] = mfma16(al, bw[0][nt][kk], acc[mt][nt]);
          acc[mt][nt] = mfma16(ah, bw[1][nt][kk], acc[mt][nt]);
        }
      }
    // ---- C -> msg LDS ----
#pragma unroll
    for (int mt = 0; mt < 2; mt++)
#pragma unroll
      for (int nt = 0; nt < 2; nt++) {
        int col = wave * 32 + nt * 16 + cl;
#pragma unroll
        for (int i = 0; i < 4; i++) {
          int row = mt * 16 + quad * 4 + i;
          msg[row * 132 + col] = acc[mt][nt][i];
        }
      }
    __syncthreads();                     // B2
    // ---- segmented max ----
    int vA = nodeof[t0];
    int vB = nodeof[tEnd - 1];
    int sNp = stradN[prv];
    int npairs = (vB - vA + 1) << 7;
    for (int p = tid; p < npairs; p += 256) {
      int v = vA + (p >> 7), col = p & 127;
      int a = offs[v], b = offs[v + 1];
      int r0 = (a > t0 ? a : t0) - t0;
      int r1 = (b < tEnd ? b : tEnd) - t0;
      float m = NEG_BIG;
      for (int r = r0; r < r1; r++) m = fmaxf(m, msg[r * 132 + col]);
      if (v == sNp) m = fmaxf(m, stradV[prv][col]);
      if (b > tEnd && tEnd < blk1) {
        stradV[par][col] = m;            // carry to next tile (only vB qualifies)
        if (col == 0) stradN[par] = v;
      } else {
        float* dp = &xout[(size_t)v * HDIM + col];
        if (a < blk0 || b > blk1) atomicMaxF(dp, m);
        else *dp = m;
      }
    }
    // next tile's B1 protects shA/msg/strad reuse
  }
}

// ---------------- final fc: out = x @ Wf + bfp ----------------
__global__ __launch_bounds__(256) void gnn_fc(const float* __restrict__ x,
    const float* __restrict__ Wf, const float* __restrict__ bfp,
    float* __restrict__ out, int N) {
  int wave = threadIdx.x >> 6, lane = threadIdx.x & 63;
  int wid = blockIdx.x * 4 + wave, nw = gridDim.x * 4;
  int k0 = lane * 2;
  float w00 = Wf[k0 * 3 + 0], w01 = Wf[k0 * 3 + 1], w02 = Wf[k0 * 3 + 2];
  float w10 = Wf[k0 * 3 + 3], w11 = Wf[k0 * 3 + 4], w12 = Wf[k0 * 3 + 5];
  float bf0 = bfp[0], bf1 = bfp[1], bf2 = bfp[2];
  for (int v = wid; v < N; v += nw) {
    f32x2 xx = *(const f32x2*)(x + (size_t)v * HDIM + k0);
    float d0 = xx.x * w00 + xx.y * w10;
    float d1 = xx.x * w01 + xx.y * w11;
    float d2 = xx.x * w02 + xx.y * w12;
#pragma unroll
    for (int s = 32; s; s >>= 1) {
      d0 += __shfl_xor(d0, s, 64);
      d1 += __shfl_xor(d1, s, 64);
      d2 += __shfl_xor(d2, s, 64);
    }
    if (lane == 0) {
      out[(size_t)v * 3 + 0] = d0 + bf0;
      out[(size_t)v * 3 + 1] = d1 + bf1;
      out[(size_t)v * 3 + 2] = d2 + bf2;
    }
  }
}

extern "C" void kernel_launch(void* const* d_in, const int* in_sizes, int n_in,
                              void* d_out, int out_size, void* d_ws, size_t ws_size,
                              hipStream_t stream) {
  const float* x_in = (const float*)d_in[0];
  const int*   ei   = (const int*)d_in[1];
  const float* W1   = (const float*)d_in[2];
  const float* b1   = (const float*)d_in[3];
  const float* W2   = (const float*)d_in[4];
  const float* b2   = (const float*)d_in[5];
  const float* Wf   = (const float*)d_in[6];
  const float* bfv  = (const float*)d_in[7];
  float* outp = (float*)d_out;
  int N = in_sizes[0] / HDIM;
  int E = in_sizes[1] / 2;
  int S = E + N;

  char* ws = (char*)d_ws;
  size_t o = 0;
  auto alloc = [&](size_t bytes) -> char* {
    char* p = ws + o;
    o += (bytes + 255) & ~(size_t)255;
    return p;
  };
  int*   deg    = (int*)alloc((size_t)N * 4);
  int*   offs   = (int*)alloc(((size_t)N + 1) * 4);
  int*   cursor = (int*)alloc((size_t)N * 4);
  int*   colsrc = (int*)alloc((size_t)S * 4);
  int*   nodeof = (int*)alloc((size_t)S * 4);
  int*   bsum   = (int*)alloc(256 * 4);
  int*   boffs  = (int*)alloc(256 * 4);
  float* cbias  = (float*)alloc((size_t)LAYERS * 256 * 4);
  float* bfp    = (float*)alloc(4 * 4);
  float* P      = (float*)alloc((size_t)N * HDIM * 4);
  float* Q      = (float*)alloc((size_t)N * HDIM * 4);
  float* xbuf   = (float*)alloc((size_t)N * HDIM * 4);
  f16*   Wc     = (f16*)alloc((size_t)LAYERS * 65536 * 2);
  f16*   W2f    = (f16*)alloc((size_t)LAYERS * 32768 * 2);
  (void)ws_size; (void)n_in; (void)out_size;

  int nb = (N + 255) / 256;
  hipMemsetAsync(deg, 0, (size_t)N * 4, stream);
  gnn_hist<<<(E + 255) / 256, 256, 0, stream>>>(ei, deg, E);
  gnn_bsum<<<nb, 256, 0, stream>>>(deg, bsum, N);
  gnn_bscan<<<1, 256, 0, stream>>>(bsum, boffs, offs, nb, N);
  gnn_scan_fin<<<nb, 256, 0, stream>>>(deg, boffs, offs, cursor, colsrc, nodeof, N);
  gnn_scatter<<<(E + 255) / 256, 256, 0, stream>>>(ei, cursor, colsrc, E);
  gnn_biasprep<<<LAYERS + 1, 256, 0, stream>>>(W1, b1, b2, Wf, bfv, cbias, bfp);
  gnn_wprep1<<<(LAYERS * 128 * 256 + 255) / 256, 256, 0, stream>>>(W1, Wc);
  gnn_wprep2<<<(LAYERS * 128 * 128 + 255) / 256, 256, 0, stream>>>(W2, W2f);

  // slots per block: ~S/1024, aligned to 32
  int spb = (((S + 1023) / 1024) + 31) & ~31;
  int NB = (S + spb - 1) / spb;
  const float* xc = x_in;
  for (int l = 0; l < LAYERS; l++) {
    gnn_pq<<<(N + 63) / 64, 256, 0, stream>>>(xc, Wc + (size_t)l * 65536, cbias + l * 256,
                                              P, Q, N, offs, spb, xbuf);
    gnn_edge3<<<NB, 256, 0, stream>>>(P, Q, offs, colsrc, nodeof, W2f + (size_t)l * 32768,
                                      xbuf, S, spb);
    xc = xbuf;
  }
  gnn_fc<<<256, 256, 0, stream>>>(xc, Wf, bfp, outp, N);
}